// Round 8
// baseline (814.555 us; speedup 1.0000x reference)
//
#include <hip/hip_runtime.h>

#define MIN_NORM 1e-15f
#define EPSV 1e-5f
#define MAXN (1.0f - EPSV)
#define NN 8192
#define DD 128

typedef unsigned short u16;
typedef __bf16 bf16x8 __attribute__((ext_vector_type(8)));
typedef float f32x4 __attribute__((ext_vector_type(4)));

__device__ __forceinline__ float wave_sum(float v) {
#pragma unroll
  for (int off = 32; off > 0; off >>= 1) v += __shfl_xor(v, off, 64);
  return v;
}

__device__ __forceinline__ float artanh_f(float x) {
  x = fminf(fmaxf(x, -1.0f + EPSV), 1.0f - EPSV);
  return 0.5f * (log1pf(x) - log1pf(-x));
}

__device__ __forceinline__ u16 f2bf(float f) {
  unsigned u = __float_as_uint(f);
  unsigned r = (u + 0x7fffu + ((u >> 16) & 1u)) >> 16;
  return (u16)r;
}
__device__ __forceinline__ float bf2f(u16 b) { return __uint_as_float(((unsigned)b) << 16); }

// monotone float<->uint encoding for atomicMax on floats (any sign)
__device__ __forceinline__ unsigned fenc(float x) {
  unsigned u = __float_as_uint(x);
  return (u & 0x80000000u) ? ~u : (u | 0x80000000u);
}
__device__ __forceinline__ float fdec(unsigned k) {
  unsigned u = (k & 0x80000000u) ? (k & 0x7fffffffu) : ~k;
  return __uint_as_float(u);
}

__device__ __forceinline__ void gload16(const u16* g, u16* l) {
  __builtin_amdgcn_global_load_lds((const __attribute__((address_space(1))) void*)(g),
                                   (__attribute__((address_space(3))) void*)(l), 16, 0, 0);
}

// ---------------------------------------------------------------------------
// adj GEMM: P[y][M][128] = adjT-tile(A) @ uT2(B), bf16, split-K=4.
// BM=64 BN=128 BK=64; 4 waves; counted-vmcnt 3-buffer ring (round-7).
// Operands pre-tiled+pre-swizzled 8-KB tiles -> linear gload16 bursts.
// ---------------------------------------------------------------------------
__global__ __launch_bounds__(256) void gemm_adj(const u16* __restrict__ A,
                                                const u16* __restrict__ Bt,
                                                float* __restrict__ Cp,
                                                int KC) {
  __shared__ __align__(16) u16 Ash[3 * 64 * 64];
  __shared__ __align__(16) u16 Bsh[3 * 128 * 64];

  const int tid = threadIdx.x;
  const int lane = tid & 63;
  const int w = tid >> 6;
  const int wm = w >> 1, wn = w & 1;
  const int lrow = lane & 15;
  const int lq = lane >> 4;
  const int m0 = blockIdx.x * 64;
  const int kt0 = (blockIdx.y * KC) >> 6;
  const int bxK = blockIdx.x * (NN >> 6);

  f32x4 acc[2][4];
#pragma unroll
  for (int a = 0; a < 2; a++)
#pragma unroll
    for (int b = 0; b < 4; b++)
#pragma unroll
      for (int r = 0; r < 4; r++) acc[a][b][r] = 0.0f;

#define STAGE(bf, tkt)                                                          \
  do {                                                                          \
    const u16* at = A + (((size_t)(bxK + (tkt))) << 12) + (lane << 3);          \
    _Pragma("unroll") for (int ii = 0; ii < 2; ii++)                            \
      gload16(at + ((ii * 4 + w) << 9), &Ash[(bf) * 4096 + ((ii * 4 + w) << 9)]); \
    const u16* bt2 = Bt + (((size_t)(tkt)) << 13) + (lane << 3);                \
    _Pragma("unroll") for (int ii = 0; ii < 4; ii++)                            \
      gload16(bt2 + ((ii * 4 + w) << 9), &Bsh[(bf) * 8192 + ((ii * 4 + w) << 9)]); \
  } while (0)

#define COMPUTE(bf)                                                             \
  do {                                                                          \
    const int abase = (bf) * 4096, bbase = (bf) * 8192;                         \
    _Pragma("unroll") for (int ks = 0; ks < 2; ks++) {                          \
      const int lc = ks * 4 + lq;                                               \
      bf16x8 af[2], bfr[4];                                                     \
      _Pragma("unroll") for (int ti = 0; ti < 2; ti++) {                        \
        int r = wm * 32 + ti * 16 + lrow;                                       \
        af[ti] = *(const bf16x8*)&Ash[abase + r * 64 + ((lc ^ (r & 7)) << 3)];  \
      }                                                                         \
      _Pragma("unroll") for (int tj = 0; tj < 4; tj++) {                        \
        int n = wn * 64 + tj * 16 + lrow;                                       \
        bfr[tj] = *(const bf16x8*)&Bsh[bbase + n * 64 + ((lc ^ (n & 7)) << 3)]; \
      }                                                                         \
      _Pragma("unroll") for (int ti = 0; ti < 2; ti++)                          \
        _Pragma("unroll") for (int tj = 0; tj < 4; tj++)                        \
          acc[ti][tj] = __builtin_amdgcn_mfma_f32_16x16x32_bf16(af[ti], bfr[tj], acc[ti][tj], 0, 0, 0); \
    }                                                                           \
  } while (0)

  const int nt = KC >> 6;
  STAGE(0, kt0);
  STAGE(1, kt0 + 1);
  for (int t = 0; t < nt - 1; t++) {
    asm volatile("s_waitcnt vmcnt(6)" ::: "memory");
    __builtin_amdgcn_s_barrier();
    if (t + 2 < nt) STAGE((t + 2) % 3, kt0 + t + 2);
    COMPUTE(t % 3);
  }
  asm volatile("s_waitcnt vmcnt(0)" ::: "memory");
  __builtin_amdgcn_s_barrier();
  COMPUTE((nt - 1) % 3);
#undef STAGE
#undef COMPUTE

  float* C = Cp + (size_t)blockIdx.y * NN * 128;
#pragma unroll
  for (int ti = 0; ti < 2; ti++)
#pragma unroll
    for (int tj = 0; tj < 4; tj++)
#pragma unroll
      for (int r = 0; r < 4; r++) {
        int row = m0 + wm * 32 + ti * 16 + lq * 4 + r;
        int col = wn * 64 + tj * 16 + lrow;
        C[(size_t)row * 128 + col] = acc[ti][tj][r];
      }
}

// ---------------------------------------------------------------------------
// Weight GEMM (K=384, split-K=1, grid 128) with FUSED rowwise_mid epilogue.
// mx = hsplit @ Wt^T accumulates fully in-block; the mobius_matvec tail +
// hyperbolic bias + mobius_add + logmap0 reduce to per-row scalars:
//   u_i = A_row*mx_i + B_row*e_i,  from row sums s2=Σmx², se=Σmx·e.
// Eliminates the 8192-block rowwise_mid dispatch + P round-trip per layer.
// xn comes from hnorm[] (stored by init/post with the identical wave_sum,
// so bit-identical to the old recompute); e = proj(expmap0(b)) precomputed.
// Output written directly as the tiled+swizzled uT2 tile (= this block).
// ---------------------------------------------------------------------------
__global__ __launch_bounds__(256) void wgemm_mid(const u16* __restrict__ A,
                                                 const u16* __restrict__ Bt,
                                                 const float* __restrict__ hnorm,
                                                 const float* __restrict__ eb,
                                                 const float* __restrict__ ey2,
                                                 u16* __restrict__ uT2) {
  __shared__ __align__(16) u16 Ash[3 * 64 * 64];
  __shared__ __align__(16) u16 Bsh[3 * 128 * 64];

  const int tid = threadIdx.x;
  const int lane = tid & 63;
  const int w = tid >> 6;
  const int wm = w >> 1, wn = w & 1;
  const int lrow = lane & 15;
  const int lq = lane >> 4;
  const int m0 = blockIdx.x * 64;
  const int srow = lane >> 3, spc = lane & 7;
  const int K = 384;
  const u16* Ap = A + (size_t)m0 * K;

  f32x4 acc[2][4];
#pragma unroll
  for (int a = 0; a < 2; a++)
#pragma unroll
    for (int b = 0; b < 4; b++)
#pragma unroll
      for (int r = 0; r < 4; r++) acc[a][b][r] = 0.0f;

#define STAGE(bf, kk)                                                           \
  do {                                                                          \
    _Pragma("unroll") for (int ii = 0; ii < 2; ii++) {                          \
      int rw = ((ii * 4 + w) << 3) + srow;                                      \
      gload16(Ap + (size_t)rw * K + (kk) + ((spc ^ (rw & 7)) << 3),             \
              &Ash[(bf) * 4096 + ((ii * 4 + w) << 9)]);                         \
    }                                                                           \
    _Pragma("unroll") for (int ii = 0; ii < 4; ii++) {                          \
      int rw = ((ii * 4 + w) << 3) + srow;                                      \
      gload16(Bt + (size_t)rw * K + (kk) + ((spc ^ (rw & 7)) << 3),             \
              &Bsh[(bf) * 8192 + ((ii * 4 + w) << 9)]);                         \
    }                                                                           \
  } while (0)

#define COMPUTE(bf)                                                             \
  do {                                                                          \
    const int abase = (bf) * 4096, bbase = (bf) * 8192;                         \
    _Pragma("unroll") for (int ks = 0; ks < 2; ks++) {                          \
      const int lc = ks * 4 + lq;                                               \
      bf16x8 af[2], bfr[4];                                                     \
      _Pragma("unroll") for (int ti = 0; ti < 2; ti++) {                        \
        int r = wm * 32 + ti * 16 + lrow;                                       \
        af[ti] = *(const bf16x8*)&Ash[abase + r * 64 + ((lc ^ (r & 7)) << 3)];  \
      }                                                                         \
      _Pragma("unroll") for (int tj = 0; tj < 4; tj++) {                        \
        int n = wn * 64 + tj * 16 + lrow;                                       \
        bfr[tj] = *(const bf16x8*)&Bsh[bbase + n * 64 + ((lc ^ (n & 7)) << 3)]; \
      }                                                                         \
      _Pragma("unroll") for (int ti = 0; ti < 2; ti++)                          \
        _Pragma("unroll") for (int tj = 0; tj < 4; tj++)                        \
          acc[ti][tj] = __builtin_amdgcn_mfma_f32_16x16x32_bf16(af[ti], bfr[tj], acc[ti][tj], 0, 0, 0); \
    }                                                                           \
  } while (0)

  const int nt = 6;  // K=384 / 64
  STAGE(0, 0);
  STAGE(1, 64);
  for (int t = 0; t < nt - 1; t++) {
    asm volatile("s_waitcnt vmcnt(6)" ::: "memory");
    __builtin_amdgcn_s_barrier();
    if (t + 2 < nt) STAGE((t + 2) % 3, (t + 2) * 64);
    COMPUTE(t % 3);
  }
  asm volatile("s_waitcnt vmcnt(0)" ::: "memory");
  __builtin_amdgcn_s_barrier();
  COMPUTE((nt - 1) % 3);
#undef STAGE
#undef COMPUTE

  // ---- fused mid epilogue ----
  float ecol[4];
#pragma unroll
  for (int tj = 0; tj < 4; tj++) ecol[tj] = eb[wn * 64 + tj * 16 + lrow];

  float* sred = (float*)Ash;  // [64 rows][4]: {s2,se}@wn0, {s2,se}@wn1 (1 KB, disjoint from buf2)
#pragma unroll
  for (int ti = 0; ti < 2; ti++)
#pragma unroll
    for (int r = 0; r < 4; r++) {
      float p2 = 0.f, pe = 0.f;
#pragma unroll
      for (int tj = 0; tj < 4; tj++) {
        float v = acc[ti][tj][r];
        p2 = fmaf(v, v, p2);
        pe = fmaf(v, ecol[tj], pe);
      }
#pragma unroll
      for (int off = 1; off < 16; off <<= 1) {
        p2 += __shfl_xor(p2, off, 64);
        pe += __shfl_xor(pe, off, 64);
      }
      if (lrow == 0) {
        int row = wm * 32 + ti * 16 + lq * 4 + r;
        sred[row * 4 + wn * 2 + 0] = p2;
        sred[row * 4 + wn * 2 + 1] = pe;
      }
    }
  __syncthreads();

  const float y2v = *ey2;
  u16* tb = uT2 + ((size_t)blockIdx.x << 13);
#pragma unroll
  for (int ti = 0; ti < 2; ti++)
#pragma unroll
    for (int r = 0; r < 4; r++) {
      int row = wm * 32 + ti * 16 + lq * 4 + r;
      float s2 = sred[row * 4 + 0] + sred[row * 4 + 2];
      float se = sred[row * 4 + 1] + sred[row * 4 + 3];
      float xn = hnorm[m0 + row];
      float mn = fmaxf(sqrtf(s2), MIN_NORM);
      float t = tanhf(mn / xn * artanh_f(xn));
      float vs = t / mn;
      float pn = fmaxf(sqrtf(vs * vs * s2), MIN_NORM);
      float sc2 = pn > MAXN ? MAXN / pn : 1.0f;
      float al = vs * sc2;             // v_i = al * mx_i
      float x2 = al * al * s2;
      float xy = al * se;
      float ca = 1.0f + 2.0f * xy + y2v;
      float cb = 1.0f - x2;
      float den = fmaxf(1.0f + 2.0f * xy + x2 * y2v, MIN_NORM);
      float tn2 = ca * ca * x2 + 2.0f * ca * cb * xy + cb * cb * y2v;
      float tn = fmaxf(sqrtf(fmaxf(tn2, 0.0f)) / den, MIN_NORM);
      float st = tn > MAXN ? MAXN / tn : 1.0f;
      float pn2 = fmaxf(tn * st, MIN_NORM);
      float gl = artanh_f(pn2) / pn2;
      float Ar = gl * st * ca * al / den;
      float Br = gl * st * cb / den;
      int c8 = (row >> 3) & 7, k7 = row & 7;
#pragma unroll
      for (int tj = 0; tj < 4; tj++) {
        int n = wn * 64 + tj * 16 + lrow;
        float u = Ar * acc[ti][tj][r] + Br * ecol[tj];
        tb[n * 64 + ((c8 ^ (n & 7)) << 3) + k7] = f2bf(u);
      }
    }
}

// fp32 adj -> tiled+swizzled bf16 adjT
__global__ __launch_bounds__(256) void cvt_tile(const float* __restrict__ src,
                                                u16* __restrict__ dst) {
  int tid = threadIdx.x;
  int xb = blockIdx.x;
  int kg = blockIdx.y;
  int ch = tid & 63;
  int rs = tid >> 6;
#pragma unroll
  for (int rr = 0; rr < 16; rr++) {
    int row = rr * 4 + rs;
    int gk = kg * 512 + ch * 8;
    const float* s = src + (size_t)(xb * 64 + row) * NN + gk;
    float4 a = *(const float4*)s;
    float4 b = *(const float4*)(s + 4);
    ushort4 d0, d1;
    d0.x = f2bf(a.x); d0.y = f2bf(a.y); d0.z = f2bf(a.z); d0.w = f2bf(a.w);
    d1.x = f2bf(b.x); d1.y = f2bf(b.y); d1.z = f2bf(b.z); d1.w = f2bf(b.w);
    u16* d = dst + (((size_t)(xb * 128 + (gk >> 6))) << 12) + row * 64 +
             ((((gk >> 3) & 7) ^ (row & 7)) << 3);
    *(ushort4*)d = d0;
    *(ushort4*)(d + 4) = d1;
  }
}

__global__ void build_wt(const float* __restrict__ W, u16* __restrict__ Wt2) {
  int idx = blockIdx.x * 256 + threadIdx.x;
  if (idx >= 4 * 128 * 128) return;
  int layer = idx >> 14;
  int n = (idx >> 7) & 127;
  int k = idx & 127;
  float e = W[idx];
  u16 hi = f2bf(e);
  u16 lo = f2bf(e - bf2f(hi));
  u16* base = Wt2 + (size_t)layer * 128 * 384 + (size_t)n * 384;
  base[k] = hi;
  base[128 + k] = hi;
  base[256 + k] = lo;
}

// hyp_b = proj(expmap0(b)) per layer, + its squared norm (matches old mid math)
__global__ __launch_bounds__(64) void prep_bias(const float* __restrict__ bconv,
                                                float* __restrict__ ebuf,
                                                float* __restrict__ ey2) {
  int layer = blockIdx.x, lane = threadIdx.x;
  const float* bvec = bconv + layer * DD;
  float b0 = bvec[lane], b1 = bvec[lane + 64];
  float bn = fmaxf(sqrtf(wave_sum(b0 * b0 + b1 * b1)), MIN_NORM);
  float gb = tanhf(bn) / bn;
  float e0 = gb * b0, e1 = gb * b1;
  float en = fmaxf(sqrtf(wave_sum(e0 * e0 + e1 * e1)), MIN_NORM);
  float sb = en > MAXN ? MAXN / en : 1.0f;
  e0 *= sb; e1 *= sb;
  float y2 = wave_sum(e0 * e0 + e1 * e1);
  ebuf[layer * DD + lane] = e0;
  ebuf[layer * DD + lane + 64] = e1;
  if (lane == 0) ey2[layer] = y2;
}

__device__ __forceinline__ void write_split(u16* hs, int i, int lane, float v0, float v1) {
  u16* row = hs + (size_t)i * 384;
  u16 h0 = f2bf(v0), h1 = f2bf(v1);
  u16 l0 = f2bf(v0 - bf2f(h0)), l1 = f2bf(v1 - bf2f(h1));
  row[lane] = h0;         row[lane + 64] = h1;
  row[128 + lane] = l0;   row[128 + 64 + lane] = l1;
  row[256 + lane] = h0;   row[256 + 64 + lane] = h1;
}

__global__ __launch_bounds__(64) void rowwise_init(const float* __restrict__ x,
                                                   float* __restrict__ h,
                                                   float* __restrict__ res,
                                                   u16* __restrict__ hsplit,
                                                   float* __restrict__ hnorm) {
  int i = blockIdx.x, lane = threadIdx.x;
  const float* xr = x + (size_t)i * DD;
  float a0 = xr[lane], a1 = xr[lane + 64];
  float n = fmaxf(sqrtf(wave_sum(a0 * a0 + a1 * a1)), MIN_NORM);
  float g = tanhf(n) / n;
  float y0 = g * a0, y1 = g * a1;
  float pn = fmaxf(sqrtf(wave_sum(y0 * y0 + y1 * y1)), MIN_NORM);
  float s = pn > MAXN ? MAXN / pn : 1.0f;
  y0 *= s; y1 *= s;
  size_t base = (size_t)i * DD;
  h[base + lane] = y0;   h[base + lane + 64] = y1;
  res[base + lane] = y0; res[base + lane + 64] = y1;
  write_split(hsplit, i, lane, y0, y1);
  float hn = fmaxf(sqrtf(wave_sum(y0 * y0 + y1 * y1)), MIN_NORM);
  if (lane == 0) hnorm[i] = hn;
}

// sum 4 split-K partials; expmap/relu/expmap chain; optional residual; write
// h + split + hnorm (identical wave_sum to what fused-mid consumes as xn).
__global__ __launch_bounds__(64) void rowwise_post(const float* __restrict__ P,
                                                   float* __restrict__ h,
                                                   float* __restrict__ res,
                                                   u16* __restrict__ hsplit,
                                                   float* __restrict__ hnorm,
                                                   int addres) {
  int i = blockIdx.x, lane = threadIdx.x;
  size_t base = (size_t)i * DD;
  float m0 = 0.f, m1 = 0.f;
#pragma unroll
  for (int sk = 0; sk < 4; sk++) {
    const float* p = P + (size_t)sk * NN * DD + base;
    m0 += p[lane];
    m1 += p[lane + 64];
  }
  float n = fmaxf(sqrtf(wave_sum(m0 * m0 + m1 * m1)), MIN_NORM);
  float g = tanhf(n) / n;
  float y0 = g * m0, y1 = g * m1;
  float pn = fmaxf(sqrtf(wave_sum(y0 * y0 + y1 * y1)), MIN_NORM);
  float s = pn > MAXN ? MAXN / pn : 1.0f;
  y0 *= s; y1 *= s;
  float hn = fmaxf(sqrtf(wave_sum(y0 * y0 + y1 * y1)), MIN_NORM);
  float gl = artanh_f(hn) / hn;
  float u0 = fmaxf(gl * y0, 0.0f), u1 = fmaxf(gl * y1, 0.0f);
  float un = fmaxf(sqrtf(wave_sum(u0 * u0 + u1 * u1)), MIN_NORM);
  float ge = tanhf(un) / un;
  float z0 = ge * u0, z1 = ge * u1;
  float zn = fmaxf(sqrtf(wave_sum(z0 * z0 + z1 * z1)), MIN_NORM);
  float sz = zn > MAXN ? MAXN / zn : 1.0f;
  z0 *= sz; z1 *= sz;
  if (addres) {
    z0 += res[base + lane];
    z1 += res[base + lane + 64];
    res[base + lane] = z0;
    res[base + lane + 64] = z1;
  }
  h[base + lane] = z0;
  h[base + lane + 64] = z1;
  write_split(hsplit, i, lane, z0, z1);
  float hn2 = fmaxf(sqrtf(wave_sum(z0 * z0 + z1 * z1)), MIN_NORM);
  if (lane == 0) hnorm[i] = hn2;
}

__global__ __launch_bounds__(256) void centroid_k(const float* __restrict__ h,
                                                  const float* __restrict__ cen,
                                                  float* __restrict__ rs) {
  __shared__ float cs[64 * 129];
  __shared__ float hs[32 * 128];
  __shared__ float y2s[64];
  int tid = threadIdx.x;
  int i0 = blockIdx.x * 32;
  for (int idx = tid; idx < 64 * 128; idx += 256) {
    int r = idx >> 7, c = idx & 127;
    cs[r * 129 + c] = cen[idx];
  }
  for (int idx = tid; idx < 32 * 128; idx += 256) hs[idx] = h[(size_t)i0 * 128 + idx];
  __syncthreads();
  if (tid < 64) {
    float s = 0.f;
    for (int k = 0; k < 128; k++) { float v = cs[tid * 129 + k]; s = fmaf(v, v, s); }
    y2s[tid] = s;
  }
  __syncthreads();
  int w = tid >> 6, lane = tid & 63;
  float dsum = 0.f;
  for (int rr = 0; rr < 8; rr++) {
    int r = w * 8 + rr;
    float dot = 0.f, x2 = 0.f;
    for (int k = 0; k < 128; k++) {
      float hk = hs[r * 128 + k];
      dot = fmaf(hk, cs[lane * 129 + k], dot);
      x2 = fmaf(hk, hk, x2);
    }
    float y2 = y2s[lane];
    float al = 1.0f - 2.0f * dot + y2;
    float be = 1.0f - x2;
    float num2 = al * al * x2 + be * be * y2 - 2.0f * al * be * dot;
    float den = fmaxf(1.0f - 2.0f * dot + x2 * y2, MIN_NORM);
    float d = fmaxf(sqrtf(fmaxf(num2, 0.0f)) / den, MIN_NORM);
    dsum += 2.0f * artanh_f(d);
  }
  atomicAdd(&rs[lane], dsum);
}

__global__ __launch_bounds__(64) void finalize_k(const float* __restrict__ rs,
                                                 float* __restrict__ out) {
  int lane = threadIdx.x;
  float r = rs[lane] * (1.0f / 8192.0f);
  float n = fmaxf(sqrtf(wave_sum(r * r)), MIN_NORM);
  float a = artanh_f(n);
  out[7 + NN * 7 + lane] = a * r / n;
  if (lane < 7) out[lane] = 1.0f;
}

// per-node scores + fold in the column max (atomicMax, monotone encoding)
__global__ __launch_bounds__(64) void scores_k(const float* __restrict__ h,
                                               const float* __restrict__ Wm,
                                               const float* __restrict__ bm,
                                               float* __restrict__ sc,
                                               unsigned* __restrict__ cmaxU) {
  int i = blockIdx.x, lane = threadIdx.x;
  const float* hr = h + (size_t)i * DD;
  float h0 = hr[lane], h1 = hr[lane + 64];
  float pn = fmaxf(sqrtf(wave_sum(h0 * h0 + h1 * h1)), MIN_NORM);
  float gl = artanh_f(pn) / pn;
  float u0 = gl * h0, u1 = gl * h1;
  float p[7];
#pragma unroll
  for (int j = 0; j < 7; j++)
    p[j] = wave_sum(u0 * Wm[j * 128 + lane] + u1 * Wm[j * 128 + lane + 64]);
  float v = p[0];
#pragma unroll
  for (int j = 1; j < 7; j++)
    if (lane == j) v = p[j];
  if (lane < 7) {
    float sv = v + bm[lane];
    sc[(size_t)i * 7 + lane] = sv;
    atomicMax(&cmaxU[lane], fenc(sv));
  }
}

// exp-sum per class: 32 blocks x 256 rows, block-reduce, 7 atomicAdds/block
__global__ __launch_bounds__(256) void sm_sum(const float* __restrict__ sc,
                                              const unsigned* __restrict__ cmaxU,
                                              float* __restrict__ csum) {
  __shared__ float buf[256][8];
  int tid = threadIdx.x;
  int i = blockIdx.x * 256 + tid;
  float cm[7];
#pragma unroll
  for (int j = 0; j < 7; j++) cm[j] = fdec(cmaxU[j]);
#pragma unroll
  for (int j = 0; j < 7; j++) buf[tid][j] = expf(sc[i * 7 + j] - cm[j]);
  __syncthreads();
  for (int off = 128; off > 0; off >>= 1) {
    if (tid < off)
#pragma unroll
      for (int j = 0; j < 7; j++) buf[tid][j] += buf[tid + off][j];
    __syncthreads();
  }
  if (tid < 7) atomicAdd(&csum[tid], buf[0][tid]);
}

__global__ __launch_bounds__(256) void sm_write(const float* __restrict__ sc,
                                                const unsigned* __restrict__ cmaxU,
                                                const float* __restrict__ csum,
                                                float* __restrict__ out) {
  int idx = blockIdx.x * 256 + threadIdx.x;
  if (idx >= NN * 7) return;
  int i = idx / 7, j = idx - i * 7;
  float cm = fdec(cmaxU[j]);
  out[idx] = expf(sc[i * 7 + j] - cm) / csum[j];
}

extern "C" void kernel_launch(void* const* d_in, const int* in_sizes, int n_in,
                              void* d_out, int out_size, void* d_ws, size_t ws_size,
                              hipStream_t stream) {
  const float* x = (const float*)d_in[0];
  const float* adj = (const float*)d_in[1];
  const float* W_conv = (const float*)d_in[3];
  const float* b_conv = (const float*)d_in[4];
  const float* centroids = (const float*)d_in[5];
  const float* W_mlp1 = (const float*)d_in[8];
  const float* b_mlp1 = (const float*)d_in[9];
  float* out = (float*)d_out;

  char* ws = (char*)d_ws;
  size_t off = 0;
  auto alloc = [&](size_t bytes) {
    void* p = ws + off;
    off = (off + bytes + 255) & ~(size_t)255;
    return p;
  };
  float* h = (float*)alloc((size_t)NN * DD * 4);
  float* res = (float*)alloc((size_t)NN * DD * 4);
  u16* hsplit = (u16*)alloc((size_t)NN * 384 * 2);
  u16* uT2 = (u16*)alloc((size_t)DD * NN * 2);
  u16* Wt2 = (u16*)alloc((size_t)4 * 128 * 384 * 2);
  float* P = (float*)alloc((size_t)4 * NN * DD * 4);
  u16* adjT = (u16*)alloc((size_t)NN * NN * 2);
  float* scores = (float*)alloc((size_t)NN * 7 * 4);
  float* hnorm = (float*)alloc((size_t)NN * 4);
  float* ebuf = (float*)alloc(4 * DD * 4);
  float* ey2 = (float*)alloc(4 * 4);
  float* zblk = (float*)alloc(768);  // rs[64] | cmaxU[7] | csum[7]
  float* rs = zblk;
  unsigned* cmaxU = (unsigned*)(zblk + 64);
  float* csum = zblk + 72;
  (void)ws_size; (void)in_sizes; (void)n_in; (void)out_size;

  hipMemsetAsync(zblk, 0, 768, stream);
  build_wt<<<(4 * 128 * 128 + 255) / 256, 256, 0, stream>>>(W_conv, Wt2);
  prep_bias<<<4, 64, 0, stream>>>(b_conv, ebuf, ey2);
  rowwise_init<<<NN, 64, 0, stream>>>(x, h, res, hsplit, hnorm);
  cvt_tile<<<dim3(128, 16), 256, 0, stream>>>(adj, adjT);
  for (int layer = 0; layer < 4; layer++) {
    wgemm_mid<<<NN / 64, 256, 0, stream>>>(hsplit, Wt2 + (size_t)layer * 128 * 384,
                                           hnorm, ebuf + layer * DD, ey2 + layer, uT2);
    gemm_adj<<<dim3(NN / 64, 4), 256, 0, stream>>>(adjT, uT2, P, NN / 4);
    rowwise_post<<<NN, 64, 0, stream>>>(P, h, res, hsplit, hnorm, (layer & 1));
  }
  centroid_k<<<256, 256, 0, stream>>>(h, centroids, rs);
  finalize_k<<<1, 64, 0, stream>>>(rs, out);
  scores_k<<<NN, 64, 0, stream>>>(h, W_mlp1, b_mlp1, scores, cmaxU);
  sm_sum<<<NN / 256, 256, 0, stream>>>(scores, cmaxU, csum);
  sm_write<<<(NN * 7 + 255) / 256, 256, 0, stream>>>(scores, cmaxU, csum, out + 7);
}